// Round 3
// baseline (212.464 us; speedup 1.0000x reference)
//
#include <hip/hip_runtime.h>

typedef __bf16 bf16_t;
typedef __bf16 bf16x8 __attribute__((ext_vector_type(8)));
typedef float f32x4 __attribute__((ext_vector_type(4)));

#define HW 16384
#define LOG2E 1.44269504088896f

__device__ __forceinline__ bf16_t f2b(float f) {
  unsigned u = __builtin_bit_cast(unsigned, f);
  u += 0x7fff + ((u >> 16) & 1);              // RTN-even
  unsigned short s = (unsigned short)(u >> 16);
  return __builtin_bit_cast(bf16_t, s);
}

// ---------------- Phase 1: Q/V/K 1x1-conv (per-batch GEMM, bf16 MFMA) ----------------
// out[o,p] = sum_c W[o,c] * x[b,c,p] + bias[o];  x staged transposed [p][c] in LDS.
__global__ __launch_bounds__(256) void qvk_kernel(
    const float* __restrict__ x, const float* __restrict__ e,
    const float* __restrict__ W1, const float* __restrict__ b1,
    const float* __restrict__ W2, const float* __restrict__ b2,
    const float* __restrict__ W3, const float* __restrict__ b3,
    bf16_t* __restrict__ Qg, bf16_t* __restrict__ Vg, bf16_t* __restrict__ Kg)
{
  __shared__ bf16_t lx[256 * 64];    // x^T tile [p][c], 128B rows, XOR swizzle   (32 KiB)
  __shared__ bf16_t le[256 * 32];    // e^T tile [p][c padded to 32], 64B rows    (16 KiB)
  __shared__ bf16_t rep[4][16 * 64]; // per-wave store repack                     ( 8 KiB)

  const int t = threadIdx.x;
  const int lane = t & 63;
  const int wv = t >> 6;
  const int b = blockIdx.x >> 6;
  const int p0 = (blockIdx.x & 63) << 8;   // 256-pixel tile

  // ---- stage x^T (transpose c<->p): strided coalesced reads, b128 swizzled writes ----
  {
    const int cq = (t >> 6) << 3;          // wave -> c-block {0,8,16,24}
    for (int half = 0; half < 2; ++half) {
      const int cc = cq + half * 32;
      for (int pp = 0; pp < 4; ++pp) {
        const int pl = pp * 64 + (t & 63);
        const float* src = x + (size_t)(b * 64 + cc) * HW + p0 + pl;
        bf16x8 v;
#pragma unroll
        for (int i = 0; i < 8; ++i) v[i] = f2b(src[(size_t)i * HW]);
        int byte = pl * 128 + cc * 2;
        byte ^= (pl & 7) << 4;
        *reinterpret_cast<bf16x8*>(reinterpret_cast<char*>(lx) + byte) = v;
      }
    }
  }
  // ---- stage e^T, channels padded 16->32 with zeros ----
  {
    const int cq = (t & 3) << 3;           // {0,8,16,24}
    const int pb = t >> 2;                 // 0..63
    for (int pp = 0; pp < 4; ++pp) {
      const int pl = pp * 64 + pb;
      bf16x8 v;
#pragma unroll
      for (int i = 0; i < 8; ++i) {
        const int c = cq + i;
        float f = (c < 16) ? e[(size_t)(b * 16 + c) * HW + p0 + pl] : 0.0f;
        v[i] = f2b(f);
      }
      *reinterpret_cast<bf16x8*>(reinterpret_cast<char*>(le) + pl * 64 + cq * 2) = v;
    }
  }
  __syncthreads();

  const int pw0 = wv << 6;                 // wave's 64-pixel slice
  const int lr = lane & 15;                // M/N index within fragment
  const int lg = lane >> 4;                // k-group
  const int kq = lg << 3;                  // k offset {0,8,16,24}

  f32x4 acc[4][4];

  auto ldx = [&](int row, int c) -> bf16x8 {
    int byte = row * 128 + c * 2;
    byte ^= (row & 7) << 4;
    return *reinterpret_cast<const bf16x8*>(reinterpret_cast<const char*>(lx) + byte);
  };

  auto store_target = [&](const float* bias, bf16_t* G) {
    const int r0 = lg << 2;
#pragma unroll
    for (int mt = 0; mt < 4; ++mt) {
      float bv[4];
#pragma unroll
      for (int r = 0; r < 4; ++r) bv[r] = bias[mt * 16 + r0 + r];
#pragma unroll
      for (int nt = 0; nt < 4; ++nt)
#pragma unroll
        for (int r = 0; r < 4; ++r)
          rep[wv][(r0 + r) * 64 + nt * 16 + lr] = f2b(acc[mt][nt][r] + bv[r]);
      asm volatile("s_waitcnt lgkmcnt(0)" ::: "memory");
#pragma unroll
      for (int half = 0; half < 2; ++half) {
        const int row = half * 8 + (lane >> 3);
        const int colb = (lane & 7) << 3;
        bf16x8 v = *reinterpret_cast<const bf16x8*>(
            reinterpret_cast<const char*>(rep[wv]) + row * 128 + colb * 2);
        *reinterpret_cast<bf16x8*>(G + (size_t)(b * 64 + mt * 16 + row) * HW + p0 + pw0 + colb) = v;
      }
      asm volatile("s_waitcnt lgkmcnt(0)" ::: "memory");
    }
  };

  // ===== V (W2) =====
#pragma unroll
  for (int mt = 0; mt < 4; ++mt)
#pragma unroll
    for (int nt = 0; nt < 4; ++nt) acc[mt][nt] = f32x4{0.f, 0.f, 0.f, 0.f};
#pragma unroll
  for (int kt = 0; kt < 2; ++kt) {
    bf16x8 A[4], Bf[4];
#pragma unroll
    for (int mt = 0; mt < 4; ++mt) {
      const float* wp = W2 + (size_t)(mt * 16 + lr) * 64 + kt * 32 + kq;
      bf16x8 a;
#pragma unroll
      for (int i = 0; i < 8; ++i) a[i] = f2b(wp[i]);
      A[mt] = a;
    }
#pragma unroll
    for (int nt = 0; nt < 4; ++nt) Bf[nt] = ldx(pw0 + nt * 16 + lr, kt * 32 + kq);
#pragma unroll
    for (int mt = 0; mt < 4; ++mt)
#pragma unroll
      for (int nt = 0; nt < 4; ++nt)
        acc[mt][nt] = __builtin_amdgcn_mfma_f32_16x16x32_bf16(A[mt], Bf[nt], acc[mt][nt], 0, 0, 0);
  }
  store_target(b2, Vg);

  // ===== K (W3) =====
#pragma unroll
  for (int mt = 0; mt < 4; ++mt)
#pragma unroll
    for (int nt = 0; nt < 4; ++nt) acc[mt][nt] = f32x4{0.f, 0.f, 0.f, 0.f};
#pragma unroll
  for (int kt = 0; kt < 2; ++kt) {
    bf16x8 A[4], Bf[4];
#pragma unroll
    for (int mt = 0; mt < 4; ++mt) {
      const float* wp = W3 + (size_t)(mt * 16 + lr) * 64 + kt * 32 + kq;
      bf16x8 a;
#pragma unroll
      for (int i = 0; i < 8; ++i) a[i] = f2b(wp[i]);
      A[mt] = a;
    }
#pragma unroll
    for (int nt = 0; nt < 4; ++nt) Bf[nt] = ldx(pw0 + nt * 16 + lr, kt * 32 + kq);
#pragma unroll
    for (int mt = 0; mt < 4; ++mt)
#pragma unroll
      for (int nt = 0; nt < 4; ++nt)
        acc[mt][nt] = __builtin_amdgcn_mfma_f32_16x16x32_bf16(A[mt], Bf[nt], acc[mt][nt], 0, 0, 0);
  }
  store_target(b3, Kg);

  // ===== Q (W1, K-dim 16 padded to 32) =====
#pragma unroll
  for (int mt = 0; mt < 4; ++mt)
#pragma unroll
    for (int nt = 0; nt < 4; ++nt) acc[mt][nt] = f32x4{0.f, 0.f, 0.f, 0.f};
  {
    bf16x8 A[4], Bf[4];
#pragma unroll
    for (int mt = 0; mt < 4; ++mt) {
      bf16x8 a;
      if (kq < 16) {
        const float* wp = W1 + (size_t)(mt * 16 + lr) * 16 + kq;
#pragma unroll
        for (int i = 0; i < 8; ++i) a[i] = f2b(wp[i]);
      } else {
#pragma unroll
        for (int i = 0; i < 8; ++i) a[i] = f2b(0.0f);
      }
      A[mt] = a;
    }
#pragma unroll
    for (int nt = 0; nt < 4; ++nt)
      Bf[nt] = *reinterpret_cast<const bf16x8*>(
          reinterpret_cast<const char*>(le) + (pw0 + nt * 16 + lr) * 64 + kq * 2);
#pragma unroll
    for (int mt = 0; mt < 4; ++mt)
#pragma unroll
      for (int nt = 0; nt < 4; ++nt)
        acc[mt][nt] = __builtin_amdgcn_mfma_f32_16x16x32_bf16(A[mt], Bf[nt], acc[mt][nt], 0, 0, 0);
  }
  store_target(b1, Qg);
}

// ---------------- Phase 2: per-n attention (S=Q V^T, softmax rows, ctx=P K) ----------------
__global__ __launch_bounds__(256) void attn_kernel(
    const bf16_t* __restrict__ Qg, const bf16_t* __restrict__ Vg,
    const bf16_t* __restrict__ Kg, float* __restrict__ out)
{
  __shared__ bf16_t bufA[128 * 128];   // Q, later K^T  (32 KiB)
  __shared__ bf16_t bufB[128 * 128];   // V, later P    (32 KiB)

  const int n = blockIdx.x;
  const int t = threadIdx.x;
  const int lane = t & 63;
  const int wv = t >> 6;
  const int lr = lane & 15;
  const int lg = lane >> 4;
  const int kq = lg << 3;

  const bf16_t* Qn = Qg + (size_t)n * HW;
  const bf16_t* Vn = Vg + (size_t)n * HW;
  const bf16_t* Kn = Kg + (size_t)n * HW;

  // stage Q -> bufA, V -> bufB (coalesced b128, swizzled rows)
  for (int it = 0; it < 8; ++it) {
    const int chunk = it * 256 + t;
    const int row = chunk >> 4;
    int byte = (row << 8) + ((chunk & 15) << 4);
    byte ^= (row & 7) << 4;
    *reinterpret_cast<bf16x8*>(reinterpret_cast<char*>(bufA) + byte) =
        *reinterpret_cast<const bf16x8*>(Qn + chunk * 8);
    *reinterpret_cast<bf16x8*>(reinterpret_cast<char*>(bufB) + byte) =
        *reinterpret_cast<const bf16x8*>(Vn + chunk * 8);
  }
  __syncthreads();

  auto ldfrag = [&](const bf16_t* buf, int row, int c) -> bf16x8 {
    int byte = (row << 8) + (c << 1);
    byte ^= (row & 7) << 4;
    return *reinterpret_cast<const bf16x8*>(reinterpret_cast<const char*>(buf) + byte);
  };

  const int h0 = wv << 5;              // wave owns 32 h-rows
  f32x4 acc[2][8];
#pragma unroll
  for (int mt = 0; mt < 2; ++mt)
#pragma unroll
    for (int nt = 0; nt < 8; ++nt) acc[mt][nt] = f32x4{0.f, 0.f, 0.f, 0.f};

  // S = Q V^T  (k = w)
#pragma unroll
  for (int kt = 0; kt < 4; ++kt) {
    bf16x8 A0 = ldfrag(bufA, h0 + lr,      kt * 32 + kq);
    bf16x8 A1 = ldfrag(bufA, h0 + 16 + lr, kt * 32 + kq);
#pragma unroll
    for (int nt = 0; nt < 8; ++nt) {
      bf16x8 Bv = ldfrag(bufB, nt * 16 + lr, kt * 32 + kq);
      acc[0][nt] = __builtin_amdgcn_mfma_f32_16x16x32_bf16(A0, Bv, acc[0][nt], 0, 0, 0);
      acc[1][nt] = __builtin_amdgcn_mfma_f32_16x16x32_bf16(A1, Bv, acc[1][nt], 0, 0, 0);
    }
  }

  // row softmax over g; keep P = exp(s-m) unnormalized, scale by 1/Z at the end
  float zrow[2][4];
#pragma unroll
  for (int mt = 0; mt < 2; ++mt) {
#pragma unroll
    for (int r = 0; r < 4; ++r) {
      float m = acc[mt][0][r];
#pragma unroll
      for (int nt = 1; nt < 8; ++nt) m = fmaxf(m, acc[mt][nt][r]);
      m = fmaxf(m, __shfl_xor(m, 1));
      m = fmaxf(m, __shfl_xor(m, 2));
      m = fmaxf(m, __shfl_xor(m, 4));
      m = fmaxf(m, __shfl_xor(m, 8));
      float z = 0.f;
#pragma unroll
      for (int nt = 0; nt < 8; ++nt) {
        float p = exp2f((acc[mt][nt][r] - m) * LOG2E);
        acc[mt][nt][r] = p;
        z += p;
      }
      z += __shfl_xor(z, 1);
      z += __shfl_xor(z, 2);
      z += __shfl_xor(z, 4);
      z += __shfl_xor(z, 8);
      zrow[mt][r] = z;
    }
  }
  __syncthreads();   // all waves done reading Q/V from LDS

  // write P (own 32 rows) into bufB, C/D layout: col=lane&15, row=4*(lane>>4)+r
#pragma unroll
  for (int mt = 0; mt < 2; ++mt) {
    const int rbase = h0 + mt * 16 + (lg << 2);
#pragma unroll
    for (int nt = 0; nt < 8; ++nt) {
#pragma unroll
      for (int r = 0; r < 4; ++r) {
        const int row = rbase + r;
        int byte = (row << 8) + ((nt * 16 + lr) << 1);
        byte ^= (row & 7) << 4;
        *reinterpret_cast<bf16_t*>(reinterpret_cast<char*>(bufB) + byte) = f2b(acc[mt][nt][r]);
      }
    }
  }
  // stage K^T into bufA: coalesced strided u16 global reads, b128 swizzled LDS writes
  for (int it = 0; it < 8; ++it) {
    const int w = t & 127;
    const int g0 = ((it << 1) + (t >> 7)) << 3;
    bf16x8 v;
#pragma unroll
    for (int i = 0; i < 8; ++i) v[i] = Kn[(g0 + i) * 128 + w];
    int byte = (w << 8) + (g0 << 1);
    byte ^= (w & 7) << 4;
    *reinterpret_cast<bf16x8*>(reinterpret_cast<char*>(bufA) + byte) = v;
  }
  __syncthreads();

  // ctx = P K   (k = g; A = P[h][g], B = K^T[w][g] -- same loader => k-map cancels)
  f32x4 acc2[2][8];
#pragma unroll
  for (int mt = 0; mt < 2; ++mt)
#pragma unroll
    for (int wt = 0; wt < 8; ++wt) acc2[mt][wt] = f32x4{0.f, 0.f, 0.f, 0.f};
#pragma unroll
  for (int kt = 0; kt < 4; ++kt) {
    bf16x8 A0 = ldfrag(bufB, h0 + lr,      kt * 32 + kq);
    bf16x8 A1 = ldfrag(bufB, h0 + 16 + lr, kt * 32 + kq);
#pragma unroll
    for (int wt = 0; wt < 8; ++wt) {
      bf16x8 Bk = ldfrag(bufA, wt * 16 + lr, kt * 32 + kq);
      acc2[0][wt] = __builtin_amdgcn_mfma_f32_16x16x32_bf16(A0, Bk, acc2[0][wt], 0, 0, 0);
      acc2[1][wt] = __builtin_amdgcn_mfma_f32_16x16x32_bf16(A1, Bk, acc2[1][wt], 0, 0, 0);
    }
  }

  float* On = out + (size_t)n * HW;
#pragma unroll
  for (int mt = 0; mt < 2; ++mt) {
    const int rbase = h0 + mt * 16 + (lg << 2);
#pragma unroll
    for (int r = 0; r < 4; ++r) {
      const float inv = 1.0f / zrow[mt][r];
#pragma unroll
      for (int wt = 0; wt < 8; ++wt)
        On[(rbase + r) * 128 + wt * 16 + lr] = acc2[mt][wt][r] * inv;
    }
  }
}

extern "C" void kernel_launch(void* const* d_in, const int* in_sizes, int n_in,
                              void* d_out, int out_size, void* d_ws, size_t ws_size,
                              hipStream_t stream) {
  const float* x  = (const float*)d_in[0];
  const float* e  = (const float*)d_in[1];
  const float* W1 = (const float*)d_in[2];
  const float* b1 = (const float*)d_in[3];
  const float* W2 = (const float*)d_in[4];
  const float* b2 = (const float*)d_in[5];
  const float* W3 = (const float*)d_in[6];
  const float* b3 = (const float*)d_in[7];
  float* out = (float*)d_out;

  bf16_t* Qg = (bf16_t*)d_ws;                       // 32 MiB each, 96 MiB total
  bf16_t* Vg = Qg + (size_t)1024 * HW;
  bf16_t* Kg = Vg + (size_t)1024 * HW;

  qvk_kernel<<<1024, 256, 0, stream>>>(x, e, W1, b1, W2, b2, W3, b3, Qg, Vg, Kg);
  attn_kernel<<<1024, 256, 0, stream>>>(Qg, Vg, Kg, out);
}